// Round 9
// baseline (272.041 us; speedup 1.0000x reference)
//
#include <hip/hip_runtime.h>
#include <stdint.h>
#include <cmath>

#define BATCH 4
#define SEQ   2048
#define DM    1024
#define NH    16
#define HDIM  64
#define MROWS (BATCH*SEQ)   // 8192
#define NQB   16            // SEQ/128 q-blocks

typedef __attribute__((ext_vector_type(8)))  __bf16 bf16x8;
typedef __attribute__((ext_vector_type(8)))  unsigned short u16x8;
typedef __attribute__((ext_vector_type(4)))  float f32x4;
typedef __attribute__((ext_vector_type(16))) float f32x16;
typedef __attribute__((ext_vector_type(4)))  unsigned int u32x4;

__device__ __forceinline__ unsigned short f2bf(float f) {
  unsigned u = __float_as_uint(f);
  u = (u + 0x7FFFu + ((u >> 16) & 1u)) >> 16;   // RNE
  return (unsigned short)u;
}

__device__ __forceinline__ f32x4 mfma_bf16(bf16x8 a, bf16x8 b, f32x4 c) {
  return __builtin_amdgcn_mfma_f32_16x16x32_bf16(a, b, c, 0, 0, 0);
}
__device__ __forceinline__ f32x16 mfma32(bf16x8 a, bf16x8 b, f32x16 c) {
  return __builtin_amdgcn_mfma_f32_32x32x16_bf16(a, b, c, 0, 0, 0);
}

__device__ __forceinline__ unsigned cvtpk(float lo, float hi) {
  unsigned r;
  asm("v_cvt_pk_bf16_f32 %0, %1, %2" : "=v"(r) : "v"(lo), "v"(hi));
  return r;
}
__device__ __forceinline__ void permswap(unsigned &a, unsigned &b) {
  asm volatile("v_permlane32_swap_b32 %0, %1" : "+v"(a), "+v"(b));
}
__device__ __forceinline__ float exp2v(float x) {
  float r;
  asm("v_exp_f32 %0, %1" : "=v"(r) : "v"(x));
  return r;
}
__device__ __forceinline__ f32x16 zero16() {
  f32x16 z;
#pragma unroll
  for (int i = 0; i < 16; ++i) z[i] = 0.f;
  return z;
}

typedef const __attribute__((address_space(1))) unsigned int* as1_u32p;
typedef __attribute__((address_space(3))) unsigned int* as3_u32p;

// 16B direct global->LDS. LDS dest: wave-uniform base + lane*16. Global src: per-lane.
__device__ __forceinline__ void gload16(const void* g, void* l) {
  __builtin_amdgcn_global_load_lds((as1_u32p)g, (as3_u32p)l, 16, 0, 0);
}

// ---------------- fp32 -> bf16 convert ----------------
__global__ void cvt_f32_bf16(const float* __restrict__ src,
                             unsigned short* __restrict__ dst, int n4) {
  int i = blockIdx.x * blockDim.x + threadIdx.x;
  int stride = gridDim.x * blockDim.x;
  for (; i < n4; i += stride) {
    float4 v = ((const float4*)src)[i];
    ushort4 o;
    o.x = f2bf(v.x); o.y = f2bf(v.y); o.z = f2bf(v.z); o.w = f2bf(v.w);
    ((ushort4*)dst)[i] = o;
  }
}

// 4 weight matrices in one launch (grid.y selects matrix)
__global__ void cvt_w4(const float* __restrict__ s0, const float* __restrict__ s1,
                       const float* __restrict__ s2, const float* __restrict__ s3,
                       unsigned short* __restrict__ d0, unsigned short* __restrict__ d1,
                       unsigned short* __restrict__ d2, unsigned short* __restrict__ d3,
                       int n4) {
  const float* src = (blockIdx.y == 0) ? s0 : (blockIdx.y == 1) ? s1 : (blockIdx.y == 2) ? s2 : s3;
  unsigned short* dst = (blockIdx.y == 0) ? d0 : (blockIdx.y == 1) ? d1 : (blockIdx.y == 2) ? d2 : d3;
  int i = blockIdx.x * blockDim.x + threadIdx.x;
  int stride = gridDim.x * blockDim.x;
  for (; i < n4; i += stride) {
    float4 v = ((const float4*)src)[i];
    ushort4 o;
    o.x = f2bf(v.x); o.y = f2bf(v.y); o.z = f2bf(v.z); o.w = f2bf(v.w);
    ((ushort4*)dst)[i] = o;
  }
}

// ---------------- shared GEMM mainloop: C(128x128) = A(128,K) * B(128,K)^T ----------------
// ROUND-4 structure (reverted): single 16KB buffers, serial stage->sync->compute.
// Round-7's 64KiB dbuf cut blocks/CU 3->2 (m132 failure mode) and regressed ~16us.
__device__ __forceinline__ void gemm_tile_mainloop(
    const unsigned short* __restrict__ A, const unsigned short* __restrict__ Bw,
    int rowBase, int colBase,
    unsigned short* As, unsigned short* Bs,
    f32x4 acc[4][4], int tid)
{
  const int wid = tid >> 6, lane = tid & 63;
  const int wm = wid >> 1, wn = wid & 1;
  const unsigned short* Atile = A + (size_t)rowBase * DM;
  const unsigned short* Btile = Bw + (size_t)colBase * DM;

  for (int k0 = 0; k0 < DM; k0 += 64) {
#pragma unroll
    for (int j = 0; j < 4; ++j) {
      int c = j * 256 + tid;
      int row = c >> 3;
      int inB = (c & 7) * 16;
      int srcE = row * DM + k0 + ((inB ^ ((row & 7) << 4)) >> 1);
      gload16(Atile + srcE, As + (size_t)(j * 256 + wid * 64) * 8);
    }
#pragma unroll
    for (int j = 0; j < 4; ++j) {
      int c = j * 256 + tid;
      int row = c >> 3;
      int inB = (c & 7) * 16;
      int srcE = row * DM + k0 + ((inB ^ ((row & 7) << 4)) >> 1);
      gload16(Btile + srcE, Bs + (size_t)(j * 256 + wid * 64) * 8);
    }
    __syncthreads();

#pragma unroll
    for (int s2 = 0; s2 < 2; ++s2) {
      bf16x8 af[4], bfv[4];
#pragma unroll
      for (int m = 0; m < 4; ++m) {
        int row = wm * 64 + m * 16 + (lane & 15);
        int off = row * 128 + ((s2 * 64 + ((lane >> 4) * 16)) ^ ((row & 7) << 4));
        af[m] = *(const bf16x8*)((const char*)As + off);
      }
#pragma unroll
      for (int n = 0; n < 4; ++n) {
        int row = wn * 64 + n * 16 + (lane & 15);
        int off = row * 128 + ((s2 * 64 + ((lane >> 4) * 16)) ^ ((row & 7) << 4));
        bfv[n] = *(const bf16x8*)((const char*)Bs + off);
      }
#pragma unroll
      for (int m = 0; m < 4; ++m)
#pragma unroll
        for (int n = 0; n < 4; ++n)
          acc[m][n] = mfma_bf16(af[m], bfv[n], acc[m][n]);
    }
    __syncthreads();
  }
}

// ---------------- QKV projection: writes Q/K/V in [B,H,S,HD] bf16 ----------------
__global__ __launch_bounds__(256, 2) void gemm_qkv(
    const unsigned short* __restrict__ xb,
    const unsigned short* __restrict__ Wqb, const unsigned short* __restrict__ Wkb,
    const unsigned short* __restrict__ Wvb,
    unsigned short* __restrict__ Qd, unsigned short* __restrict__ Kd,
    unsigned short* __restrict__ Vd)
{
  __shared__ unsigned short As[128 * 64];
  __shared__ unsigned short Bs[128 * 64];
  const int tid = threadIdx.x;
  const int z = blockIdx.z;
  const unsigned short* W = (z == 0) ? Wqb : (z == 1) ? Wkb : Wvb;
  unsigned short* dst = (z == 0) ? Qd : (z == 1) ? Kd : Vd;
  const int rowBase = blockIdx.x * 128, colBase = blockIdx.y * 128;

  f32x4 acc[4][4];
#pragma unroll
  for (int m = 0; m < 4; ++m)
#pragma unroll
    for (int n = 0; n < 4; ++n) acc[m][n] = (f32x4){0.f, 0.f, 0.f, 0.f};

  gemm_tile_mainloop(xb, W, rowBase, colBase, As, Bs, acc, tid);

  const int wid = tid >> 6, lane = tid & 63;
  const int wm = wid >> 1, wn = wid & 1;
#pragma unroll
  for (int m = 0; m < 4; ++m)
#pragma unroll
    for (int n = 0; n < 4; ++n)
#pragma unroll
      for (int r = 0; r < 4; ++r) {
        int grow = rowBase + wm * 64 + m * 16 + ((lane >> 4) * 4) + r;  // b*SEQ+s
        int gcol = colBase + wn * 64 + n * 16 + (lane & 15);            // h*64+hd
        int b = grow >> 11, s = grow & (SEQ - 1);
        int h = gcol >> 6, hd = gcol & 63;
        dst[(((size_t)(b * NH + h)) * SEQ + s) * HDIM + hd] = f2bf(acc[m][n][r]);
      }
}

// ---------------- output projection: out = ctx @ Wo^T + bo (fp32 out) ----------------
__global__ __launch_bounds__(256, 2) void gemm_out(
    const unsigned short* __restrict__ ctx, const unsigned short* __restrict__ Wob,
    const float* __restrict__ bo, float* __restrict__ out)
{
  __shared__ unsigned short As[128 * 64];
  __shared__ unsigned short Bs[128 * 64];
  const int tid = threadIdx.x;
  const int rowBase = blockIdx.x * 128, colBase = blockIdx.y * 128;

  f32x4 acc[4][4];
#pragma unroll
  for (int m = 0; m < 4; ++m)
#pragma unroll
    for (int n = 0; n < 4; ++n) acc[m][n] = (f32x4){0.f, 0.f, 0.f, 0.f};

  gemm_tile_mainloop(ctx, Wob, rowBase, colBase, As, Bs, acc, tid);

  const int wid = tid >> 6, lane = tid & 63;
  const int wm = wid >> 1, wn = wid & 1;
#pragma unroll
  for (int m = 0; m < 4; ++m)
#pragma unroll
    for (int n = 0; n < 4; ++n)
#pragma unroll
      for (int r = 0; r < 4; ++r) {
        int grow = rowBase + wm * 64 + m * 16 + ((lane >> 4) * 4) + r;
        int gcol = colBase + wn * 64 + n * 16 + (lane & 15);
        out[(size_t)grow * DM + gcol] = acc[m][n][r] + bo[gcol];
      }
}

// ---------------- V transpose: [B,H,S,HD] -> [B,H,HD,S] ----------------
__global__ void transpose_v(const unsigned short* __restrict__ Vd,
                            unsigned short* __restrict__ VT)
{
  __shared__ unsigned short tile[64 * 72];   // [s][d], pad 72
  const int tid = threadIdx.x;
  const int bh = blockIdx.y, s0 = blockIdx.x * 64;
  const unsigned short* src = Vd + (size_t)bh * SEQ * HDIM + (size_t)s0 * HDIM;
#pragma unroll
  for (int j = 0; j < 2; ++j) {
    int c = j * 256 + tid;
    int r = c >> 3, c0 = (c & 7) * 8;
    *(u16x8*)(tile + r * 72 + c0) = *(const u16x8*)(src + r * HDIM + c0);
  }
  __syncthreads();
  unsigned short* dst = VT + (size_t)bh * HDIM * SEQ + s0;
#pragma unroll
  for (int j = 0; j < 2; ++j) {
    int c = j * 256 + tid;
    int d = c >> 3, c0 = (c & 7) * 8;
    u16x8 v;
#pragma unroll
    for (int e = 0; e < 8; ++e) v[e] = tile[(c0 + e) * 72 + d];
    *(u16x8*)(dst + (size_t)d * SEQ + c0) = v;
  }
}

// ---------------- causal flash attention: KV-parity split, 8 warps ----------------
// grid (8, 64) x 512 threads. Block processes qb = blockIdx.x then 15-blockIdx.x.
// Warps 0-3 (grp 0): q-rows wq*32, EVEN kv tiles. Warps 4-7 (grp 1): same q, ODD
// tiles. Each superstep stages K/V for both parities (each tile staged once ->
// HBM unchanged); LDS 64KiB (4 K bufs + 4 V bufs x 8KB, dbuf x parity).
// nt = 2qb+2 is even -> supersteps nss = qb+1, no tail. Per-qb merge of the two
// partial (m,l,O) states via LDS (exp2(-inf)=0 makes empty odd-warps a no-op).
__global__ __launch_bounds__(512, 4) void attn_fwd4(
    const unsigned short* __restrict__ Qg, const unsigned short* __restrict__ Kg,
    const unsigned short* __restrict__ VTg, unsigned short* __restrict__ ctx)
{
  __shared__ unsigned short smem[32768];  // 64 KiB

  const int tid = threadIdx.x, wid = tid >> 6, lane = tid & 63;
  const int grp = wid >> 2, wq = wid & 3;
  const int hi = lane >> 5, lq = lane & 31;
  const int bh = blockIdx.y;
  const unsigned short* Qp = Qg  + (size_t)bh * SEQ * HDIM;
  const unsigned short* Kp = Kg  + (size_t)bh * SEQ * HDIM;
  const unsigned short* Vp = VTg + (size_t)bh * HDIM * SEQ;   // [d][s]
  const int b = bh >> 4, h = bh & 15;
  const float C2 = 0.18033688f;   // 0.125 * log2(e)

  // staging geometry: 512 threads cover one 64x128B tile (512 x 16B chunks)
  const int sRow = tid >> 3;                                   // 0..63
  const int sSwz = ((((tid & 7) * 16) ^ ((sRow & 7) << 4)) >> 1); // elems
  const int sDst = wid * 512;                                  // elems (lane*16B added by HW)

  // LDS read byte-offsets (rows lq / lq+32 of a 64x128B swizzled tile)
  int off0[4], off1[4];
#pragma unroll
  for (int ks = 0; ks < 4; ++ks) {
    int col = ks * 32 + hi * 16;
    off0[ks] = lq * 128 + (col ^ ((lq & 7) << 4));
    off1[ks] = (lq + 32) * 128 + (col ^ ((lq & 7) << 4));  // (lq+32)&7 == lq&7
  }

  for (int half = 0; half < 2; ++half) {
    const int qb = half == 0 ? (int)blockIdx.x : (NQB - 1 - (int)blockIdx.x);
    const int qw0 = qb * 128 + wq * 32;       // warp's first q row

    // staging source pointers (advance 2 tiles = 128 rows/cols per superstep)
    const unsigned short* kSrc[2];
    const unsigned short* vSrc[2];
#pragma unroll
    for (int p = 0; p < 2; ++p) {
      kSrc[p] = Kp + (size_t)(p * 64 + sRow) * HDIM + sSwz;
      vSrc[p] = Vp + (size_t)sRow * SEQ + p * 64 + sSwz;
    }
    // stage superstep into dbuf d: K bufs at (d*2+p)*4096 elems, V at +16384
    auto stageSS = [&](int d) {
#pragma unroll
      for (int p = 0; p < 2; ++p) {
        gload16(kSrc[p], smem + (d * 2 + p) * 4096 + sDst);
        kSrc[p] += 128 * HDIM;
      }
#pragma unroll
      for (int p = 0; p < 2; ++p) {
        gload16(vSrc[p], smem + 16384 + (d * 2 + p) * 4096 + sDst);
        vSrc[p] += 128;
      }
    };

    // Q B-frags: lane q=lq, d = ks*16 + hi*8 + j (same for both groups)
    bf16x8 qf[4];
    {
      const unsigned short* qrow = Qp + (size_t)(qw0 + lq) * HDIM + hi * 8;
#pragma unroll
      for (int ks = 0; ks < 4; ++ks) qf[ks] = *(const bf16x8*)(qrow + ks * 16);
    }

    f32x16 o0 = zero16(), o1 = zero16();
    float m_run = -INFINITY, l_run = 0.f, mc2 = 0.f;
    const int nss = qb + 1;     // supersteps; tiles 2ts (grp0), 2ts+1 (grp1)

    stageSS(0);
    asm volatile("s_waitcnt vmcnt(0)" ::: "memory");
    __builtin_amdgcn_s_barrier();

    for (int ts = 0; ts < nss; ++ts) {
      const int cur = ts & 1;
      if (ts + 1 < nss) stageSS(cur ^ 1);

      const int t = 2 * ts + grp;   // this warp's tile
      if (t * 64 <= qw0 + 31) {     // at least one visible key
        const char* Kl = (const char*)smem + (cur * 2 + grp) * 8192;
        f32x16 s0 = zero16(), s1 = zero16();
        __builtin_amdgcn_s_setprio(1);
#pragma unroll
        for (int ks = 0; ks < 4; ++ks) {
          bf16x8 a0 = *(const bf16x8*)(Kl + off0[ks]);
          bf16x8 a1 = *(const bf16x8*)(Kl + off1[ks]);
          s0 = mfma32(a0, qf[ks], s0);
          s1 = mfma32(a1, qf[ks], s1);
        }
        __builtin_amdgcn_s_setprio(0);

        // causal mask (raw scores; 1/8 scale folded into exp)
        if (t * 64 + 63 > qw0) {
          const int q = qw0 + lq;
          const int kb = t * 64 + 4 * hi;
#pragma unroll
          for (int r = 0; r < 16; ++r) {
            int k0 = kb + (r & 3) + 8 * (r >> 2);
            if (k0 > q)      s0[r] = -INFINITY;
            if (k0 + 32 > q) s1[r] = -INFINITY;
          }
        }

        // online softmax, lane-local + 1 cross-half exchange
        float pmax = fmaxf(s0[0], s0[1]);
#pragma unroll
        for (int r = 2; r < 16; r += 2) pmax = fmaxf(pmax, fmaxf(s0[r], s0[r + 1]));
#pragma unroll
        for (int r = 0; r < 16; r += 2) pmax = fmaxf(pmax, fmaxf(s1[r], s1[r + 1]));
        pmax = fmaxf(pmax, __shfl_xor(pmax, 32, 64));

        if (!__all(pmax - m_run <= 64.0f)) {     // defer-max THR: e^(64*0.125)=e^8
          float mn = fmaxf(m_run, pmax);
          float alpha = exp2v((m_run - mn) * C2);
          l_run *= alpha;
#pragma unroll
          for (int r = 0; r < 16; ++r) { o0[r] *= alpha; o1[r] *= alpha; }
          m_run = mn;
          mc2 = mn * C2;
        }

        float rsum = 0.f;
#pragma unroll
        for (int r = 0; r < 16; ++r) {
          float p = exp2v(__builtin_fmaf(s0[r], C2, -mc2));
          s0[r] = p; rsum += p;
        }
#pragma unroll
        for (int r = 0; r < 16; ++r) {
          float p = exp2v(__builtin_fmaf(s1[r], C2, -mc2));
          s1[r] = p; rsum += p;
        }
        rsum += __shfl_xor(rsum, 32, 64);
        l_run += rsum;

        // P -> bf16 B-frags via cvt_pk + permlane32_swap (T12)
        bf16x8 pfr[4];
#pragma unroll
        for (int h2 = 0; h2 < 2; ++h2) {
          {
            unsigned va = cvtpk(s0[h2 * 8 + 0], s0[h2 * 8 + 1]);
            unsigned vb = cvtpk(s0[h2 * 8 + 4], s0[h2 * 8 + 5]);
            unsigned vc = cvtpk(s0[h2 * 8 + 2], s0[h2 * 8 + 3]);
            unsigned vd = cvtpk(s0[h2 * 8 + 6], s0[h2 * 8 + 7]);
            permswap(va, vb); permswap(vc, vd);
            u32x4 tt; tt.x = va; tt.y = vc; tt.z = vb; tt.w = vd;
            pfr[h2] = __builtin_bit_cast(bf16x8, tt);
          }
          {
            unsigned va = cvtpk(s1[h2 * 8 + 0], s1[h2 * 8 + 1]);
            unsigned vb = cvtpk(s1[h2 * 8 + 4], s1[h2 * 8 + 5]);
            unsigned vc = cvtpk(s1[h2 * 8 + 2], s1[h2 * 8 + 3]);
            unsigned vd = cvtpk(s1[h2 * 8 + 6], s1[h2 * 8 + 7]);
            permswap(va, vb); permswap(vc, vd);
            u32x4 tt; tt.x = va; tt.y = vc; tt.z = vb; tt.w = vd;
            pfr[2 + h2] = __builtin_bit_cast(bf16x8, tt);
          }
        }

        // PV: O^T[64 d][32 q] += V^T * P^T
        const char* Vl = (const char*)smem + 32768 + (cur * 2 + grp) * 8192;
        __builtin_amdgcn_s_setprio(1);
#pragma unroll
        for (int ks = 0; ks < 4; ++ks) {
          bf16x8 va0 = *(const bf16x8*)(Vl + off0[ks]);
          bf16x8 va1 = *(const bf16x8*)(Vl + off1[ks]);
          o0 = mfma32(va0, pfr[ks], o0);
          o1 = mfma32(va1, pfr[ks], o1);
        }
        __builtin_amdgcn_s_setprio(0);
      }

      asm volatile("s_waitcnt vmcnt(0)" ::: "memory");
      __builtin_amdgcn_s_barrier();
    }

    // ---- merge odd-group partials into even group (per qb) ----
    float* MF = (float*)smem;
    if (grp == 1) {
      if (hi == 0) {
        MF[wq * 32 + lq] = m_run;
        MF[128 + wq * 32 + lq] = l_run;
      }
      int base = 256 + (wq * 64 + lane) * 32;
#pragma unroll
      for (int r = 0; r < 16; ++r) {
        MF[base + r] = o0[r];
        MF[base + 16 + r] = o1[r];
      }
    }
    __syncthreads();
    float invl = 0.f;
    if (grp == 0) {
      float m_b = MF[wq * 32 + lq];
      float l_b = MF[128 + wq * 32 + lq];
      float mn = fmaxf(m_run, m_b);
      float aA = exp2v((m_run - mn) * C2);
      float aB = exp2v((m_b - mn) * C2);
      l_run = l_run * aA + l_b * aB;
      int base = 256 + (wq * 64 + lane) * 32;
#pragma unroll
      for (int r = 0; r < 16; ++r) {
        o0[r] = o0[r] * aA + MF[base + r] * aB;
        o1[r] = o1[r] * aA + MF[base + 16 + r] * aB;
      }
      invl = 1.0f / l_run;
    }
    __syncthreads();

    // ---- epilogue: even group normalizes + writes Ot; all store [B,S,D] ----
    unsigned short* Ot = smem;            // [128 q][64 d] bf16, XOR-swizzled rows
    if (grp == 0) {
      const int q = wq * 32 + lq;
#pragma unroll
      for (int r2 = 0; r2 < 16; r2 += 2) {
        int d = (r2 & 3) + 8 * (r2 >> 2) + 4 * hi;
        unsigned w0 = cvtpk(o0[r2] * invl, o0[r2 + 1] * invl);
        *(unsigned*)((char*)Ot + q * 128 + ((2 * d) ^ ((q & 7) << 4))) = w0;
        int d2 = d + 32;
        unsigned w1 = cvtpk(o1[r2] * invl, o1[r2 + 1] * invl);
        *(unsigned*)((char*)Ot + q * 128 + ((2 * d2) ^ ((q & 7) << 4))) = w1;
      }
    }
    __syncthreads();

#pragma unroll
    for (int i = 0; i < 2; ++i) {
      int idx = i * 512 + tid;
      int qq = idx >> 3, c16 = (idx & 7) * 8;
      bf16x8 v = *(const bf16x8*)((const char*)Ot + qq * 128 + ((2 * c16) ^ ((qq & 7) << 4)));
      *(bf16x8*)(ctx + ((size_t)(b * SEQ) + qb * 128 + qq) * DM + h * 64 + c16) = v;
    }
    __syncthreads();   // protect smem before next half's staging
  }
}

// ---------------- launch ----------------
extern "C" void kernel_launch(void* const* d_in, const int* in_sizes, int n_in,
                              void* d_out, int out_size, void* d_ws, size_t ws_size,
                              hipStream_t stream)
{
  (void)in_sizes; (void)n_in; (void)out_size; (void)ws_size;
  const float* x  = (const float*)d_in[0];
  const float* Wq = (const float*)d_in[1];
  const float* Wk = (const float*)d_in[2];
  const float* Wv = (const float*)d_in[3];
  const float* Wo = (const float*)d_in[4];
  const float* bo = (const float*)d_in[5];
  float* out = (float*)d_out;

  char* ws = (char*)d_ws;
  unsigned short* xb  = (unsigned short*)(ws);                        // 16 MiB (x bf16; reused as V^T)
  unsigned short* Wqb = (unsigned short*)(ws + (size_t)16 * 1048576);
  unsigned short* Wkb = (unsigned short*)(ws + (size_t)18 * 1048576);
  unsigned short* Wvb = (unsigned short*)(ws + (size_t)20 * 1048576);
  unsigned short* Wob = (unsigned short*)(ws + (size_t)22 * 1048576);
  unsigned short* Qd  = (unsigned short*)(ws + (size_t)24 * 1048576); // [B,H,S,HD]
  unsigned short* Kd  = (unsigned short*)(ws + (size_t)40 * 1048576);
  unsigned short* Vd  = (unsigned short*)(ws + (size_t)56 * 1048576);
  unsigned short* ctxb= (unsigned short*)(ws + (size_t)72 * 1048576); // [B,S,D]
  unsigned short* VT  = xb;                                           // [B,H,HD,S] (x dead after gemm_qkv)

  cvt_f32_bf16<<<2048, 256, 0, stream>>>(x, xb, MROWS * DM / 4);
  cvt_w4<<<dim3(64, 4), 256, 0, stream>>>(Wq, Wk, Wv, Wo, Wqb, Wkb, Wvb, Wob, DM * DM / 4);

  gemm_qkv<<<dim3(MROWS / 128, DM / 128, 3), 256, 0, stream>>>(xb, Wqb, Wkb, Wvb, Qd, Kd, Vd);
  transpose_v<<<dim3(SEQ / 64, BATCH * NH), 256, 0, stream>>>(Vd, VT);
  attn_fwd4<<<dim3(NQB / 2, BATCH * NH), 512, 0, stream>>>(Qd, Kd, VT, ctxb);
  gemm_out<<<dim3(MROWS / 128, DM / 128, 1), 256, 0, stream>>>(ctxb, Wob, bo, out);
}

// Round 10
// 250.313 us; speedup vs baseline: 1.0868x; 1.0868x over previous
//
#include <hip/hip_runtime.h>
#include <stdint.h>
#include <cmath>

#define BATCH 4
#define SEQ   2048
#define DM    1024
#define NH    16
#define HDIM  64
#define MROWS (BATCH*SEQ)   // 8192
#define NQB   16            // SEQ/128 q-blocks

typedef __attribute__((ext_vector_type(8)))  __bf16 bf16x8;
typedef __attribute__((ext_vector_type(8)))  unsigned short u16x8;
typedef __attribute__((ext_vector_type(4)))  float f32x4;
typedef __attribute__((ext_vector_type(16))) float f32x16;
typedef __attribute__((ext_vector_type(4)))  unsigned int u32x4;

__device__ __forceinline__ unsigned short f2bf(float f) {
  unsigned u = __float_as_uint(f);
  u = (u + 0x7FFFu + ((u >> 16) & 1u)) >> 16;   // RNE
  return (unsigned short)u;
}

__device__ __forceinline__ f32x4 mfma_bf16(bf16x8 a, bf16x8 b, f32x4 c) {
  return __builtin_amdgcn_mfma_f32_16x16x32_bf16(a, b, c, 0, 0, 0);
}
__device__ __forceinline__ f32x16 mfma32(bf16x8 a, bf16x8 b, f32x16 c) {
  return __builtin_amdgcn_mfma_f32_32x32x16_bf16(a, b, c, 0, 0, 0);
}

__device__ __forceinline__ unsigned cvtpk(float lo, float hi) {
  unsigned r;
  asm("v_cvt_pk_bf16_f32 %0, %1, %2" : "=v"(r) : "v"(lo), "v"(hi));
  return r;
}
__device__ __forceinline__ void permswap(unsigned &a, unsigned &b) {
  asm volatile("v_permlane32_swap_b32 %0, %1" : "+v"(a), "+v"(b));
}
__device__ __forceinline__ float exp2v(float x) {
  float r;
  asm("v_exp_f32 %0, %1" : "=v"(r) : "v"(x));
  return r;
}
__device__ __forceinline__ f32x16 zero16() {
  f32x16 z;
#pragma unroll
  for (int i = 0; i < 16; ++i) z[i] = 0.f;
  return z;
}

typedef const __attribute__((address_space(1))) unsigned int* as1_u32p;
typedef __attribute__((address_space(3))) unsigned int* as3_u32p;

// 16B direct global->LDS. LDS dest: wave-uniform base + lane*16. Global src: per-lane.
__device__ __forceinline__ void gload16(const void* g, void* l) {
  __builtin_amdgcn_global_load_lds((as1_u32p)g, (as3_u32p)l, 16, 0, 0);
}

// ---------------- fp32 -> bf16 convert ----------------
__global__ void cvt_f32_bf16(const float* __restrict__ src,
                             unsigned short* __restrict__ dst, int n4) {
  int i = blockIdx.x * blockDim.x + threadIdx.x;
  int stride = gridDim.x * blockDim.x;
  for (; i < n4; i += stride) {
    float4 v = ((const float4*)src)[i];
    ushort4 o;
    o.x = f2bf(v.x); o.y = f2bf(v.y); o.z = f2bf(v.z); o.w = f2bf(v.w);
    ((ushort4*)dst)[i] = o;
  }
}

// 4 weight matrices in one launch (grid.y selects matrix)
__global__ void cvt_w4(const float* __restrict__ s0, const float* __restrict__ s1,
                       const float* __restrict__ s2, const float* __restrict__ s3,
                       unsigned short* __restrict__ d0, unsigned short* __restrict__ d1,
                       unsigned short* __restrict__ d2, unsigned short* __restrict__ d3,
                       int n4) {
  const float* src = (blockIdx.y == 0) ? s0 : (blockIdx.y == 1) ? s1 : (blockIdx.y == 2) ? s2 : s3;
  unsigned short* dst = (blockIdx.y == 0) ? d0 : (blockIdx.y == 1) ? d1 : (blockIdx.y == 2) ? d2 : d3;
  int i = blockIdx.x * blockDim.x + threadIdx.x;
  int stride = gridDim.x * blockDim.x;
  for (; i < n4; i += stride) {
    float4 v = ((const float4*)src)[i];
    ushort4 o;
    o.x = f2bf(v.x); o.y = f2bf(v.y); o.z = f2bf(v.z); o.w = f2bf(v.w);
    ((ushort4*)dst)[i] = o;
  }
}

// ---------------- shared GEMM mainloop: C(128x128) = A(128,K) * B(128,K)^T ----------------
// ROUND-4 structure: single 16KB buffers, serial stage->sync->compute.
// (64KiB dbuf regressed: blocks/CU 3->2, m132 failure mode.)
__device__ __forceinline__ void gemm_tile_mainloop(
    const unsigned short* __restrict__ A, const unsigned short* __restrict__ Bw,
    int rowBase, int colBase,
    unsigned short* As, unsigned short* Bs,
    f32x4 acc[4][4], int tid)
{
  const int wid = tid >> 6, lane = tid & 63;
  const int wm = wid >> 1, wn = wid & 1;
  const unsigned short* Atile = A + (size_t)rowBase * DM;
  const unsigned short* Btile = Bw + (size_t)colBase * DM;

  for (int k0 = 0; k0 < DM; k0 += 64) {
#pragma unroll
    for (int j = 0; j < 4; ++j) {
      int c = j * 256 + tid;
      int row = c >> 3;
      int inB = (c & 7) * 16;
      int srcE = row * DM + k0 + ((inB ^ ((row & 7) << 4)) >> 1);
      gload16(Atile + srcE, As + (size_t)(j * 256 + wid * 64) * 8);
    }
#pragma unroll
    for (int j = 0; j < 4; ++j) {
      int c = j * 256 + tid;
      int row = c >> 3;
      int inB = (c & 7) * 16;
      int srcE = row * DM + k0 + ((inB ^ ((row & 7) << 4)) >> 1);
      gload16(Btile + srcE, Bs + (size_t)(j * 256 + wid * 64) * 8);
    }
    __syncthreads();

#pragma unroll
    for (int s2 = 0; s2 < 2; ++s2) {
      bf16x8 af[4], bfv[4];
#pragma unroll
      for (int m = 0; m < 4; ++m) {
        int row = wm * 64 + m * 16 + (lane & 15);
        int off = row * 128 + ((s2 * 64 + ((lane >> 4) * 16)) ^ ((row & 7) << 4));
        af[m] = *(const bf16x8*)((const char*)As + off);
      }
#pragma unroll
      for (int n = 0; n < 4; ++n) {
        int row = wn * 64 + n * 16 + (lane & 15);
        int off = row * 128 + ((s2 * 64 + ((lane >> 4) * 16)) ^ ((row & 7) << 4));
        bfv[n] = *(const bf16x8*)((const char*)Bs + off);
      }
#pragma unroll
      for (int m = 0; m < 4; ++m)
#pragma unroll
        for (int n = 0; n < 4; ++n)
          acc[m][n] = mfma_bf16(af[m], bfv[n], acc[m][n]);
    }
    __syncthreads();
  }
}

// ---------------- QKV projection: writes Q/K/V in [B,H,S,HD] bf16 ----------------
__global__ __launch_bounds__(256, 2) void gemm_qkv(
    const unsigned short* __restrict__ xb,
    const unsigned short* __restrict__ Wqb, const unsigned short* __restrict__ Wkb,
    const unsigned short* __restrict__ Wvb,
    unsigned short* __restrict__ Qd, unsigned short* __restrict__ Kd,
    unsigned short* __restrict__ Vd)
{
  __shared__ unsigned short As[128 * 64];
  __shared__ unsigned short Bs[128 * 64];
  const int tid = threadIdx.x;
  const int z = blockIdx.z;
  const unsigned short* W = (z == 0) ? Wqb : (z == 1) ? Wkb : Wvb;
  unsigned short* dst = (z == 0) ? Qd : (z == 1) ? Kd : Vd;
  const int rowBase = blockIdx.x * 128, colBase = blockIdx.y * 128;

  f32x4 acc[4][4];
#pragma unroll
  for (int m = 0; m < 4; ++m)
#pragma unroll
    for (int n = 0; n < 4; ++n) acc[m][n] = (f32x4){0.f, 0.f, 0.f, 0.f};

  gemm_tile_mainloop(xb, W, rowBase, colBase, As, Bs, acc, tid);

  const int wid = tid >> 6, lane = tid & 63;
  const int wm = wid >> 1, wn = wid & 1;
#pragma unroll
  for (int m = 0; m < 4; ++m)
#pragma unroll
    for (int n = 0; n < 4; ++n)
#pragma unroll
      for (int r = 0; r < 4; ++r) {
        int grow = rowBase + wm * 64 + m * 16 + ((lane >> 4) * 4) + r;  // b*SEQ+s
        int gcol = colBase + wn * 64 + n * 16 + (lane & 15);            // h*64+hd
        int b = grow >> 11, s = grow & (SEQ - 1);
        int h = gcol >> 6, hd = gcol & 63;
        dst[(((size_t)(b * NH + h)) * SEQ + s) * HDIM + hd] = f2bf(acc[m][n][r]);
      }
}

// ---------------- output projection: out = ctx @ Wo^T + bo (fp32 out) ----------------
__global__ __launch_bounds__(256, 2) void gemm_out(
    const unsigned short* __restrict__ ctx, const unsigned short* __restrict__ Wob,
    const float* __restrict__ bo, float* __restrict__ out)
{
  __shared__ unsigned short As[128 * 64];
  __shared__ unsigned short Bs[128 * 64];
  const int tid = threadIdx.x;
  const int rowBase = blockIdx.x * 128, colBase = blockIdx.y * 128;

  f32x4 acc[4][4];
#pragma unroll
  for (int m = 0; m < 4; ++m)
#pragma unroll
    for (int n = 0; n < 4; ++n) acc[m][n] = (f32x4){0.f, 0.f, 0.f, 0.f};

  gemm_tile_mainloop(ctx, Wob, rowBase, colBase, As, Bs, acc, tid);

  const int wid = tid >> 6, lane = tid & 63;
  const int wm = wid >> 1, wn = wid & 1;
#pragma unroll
  for (int m = 0; m < 4; ++m)
#pragma unroll
    for (int n = 0; n < 4; ++n)
#pragma unroll
      for (int r = 0; r < 4; ++r) {
        int grow = rowBase + wm * 64 + m * 16 + ((lane >> 4) * 4) + r;
        int gcol = colBase + wn * 64 + n * 16 + (lane & 15);
        out[(size_t)grow * DM + gcol] = acc[m][n][r] + bo[gcol];
      }
}

// ---------------- V transpose: [B,H,S,HD] -> [B,H,HD,S] ----------------
__global__ void transpose_v(const unsigned short* __restrict__ Vd,
                            unsigned short* __restrict__ VT)
{
  __shared__ unsigned short tile[64 * 72];   // [s][d], pad 72
  const int tid = threadIdx.x;
  const int bh = blockIdx.y, s0 = blockIdx.x * 64;
  const unsigned short* src = Vd + (size_t)bh * SEQ * HDIM + (size_t)s0 * HDIM;
#pragma unroll
  for (int j = 0; j < 2; ++j) {
    int c = j * 256 + tid;
    int r = c >> 3, c0 = (c & 7) * 8;
    *(u16x8*)(tile + r * 72 + c0) = *(const u16x8*)(src + r * HDIM + c0);
  }
  __syncthreads();
  unsigned short* dst = VT + (size_t)bh * HDIM * SEQ + s0;
#pragma unroll
  for (int j = 0; j < 2; ++j) {
    int c = j * 256 + tid;
    int d = c >> 3, c0 = (c & 7) * 8;
    u16x8 v;
#pragma unroll
    for (int e = 0; e < 8; ++e) v[e] = tile[(c0 + e) * 72 + d];
    *(u16x8*)(dst + (size_t)d * SEQ + c0) = v;
  }
}

// ---------------- causal flash attention: ROUND-7 structure, 3 blocks/CU ----------
// grid (8, 64) x 256 thr. Block processes qb = blockIdx.x then 15-blockIdx.x.
// 4 warps x 32 q-rows. K/V triple-buffered; depth-2 prefetch; wait-then-barrier
// counted vmcnt(4). __launch_bounds__(256,3): cap ~170 regs/wave -> 12 waves/CU
// (round 7's (256,2) left residency at 2 blocks/CU via ~192 regs/wave; round 9's
// (512,4) cap of 128 caused catastrophic scratch spills - +76MB HBM traffic).
__global__ __launch_bounds__(256, 3) void attn_fwd3(
    const unsigned short* __restrict__ Qg, const unsigned short* __restrict__ Kg,
    const unsigned short* __restrict__ VTg, unsigned short* __restrict__ ctx)
{
  __shared__ unsigned short smem[24576];  // 48KB: K bufs [0,12288), V^T bufs [12288,24576)

  const int tid = threadIdx.x, wid = tid >> 6, lane = tid & 63;
  const int hi = lane >> 5, lq = lane & 31;
  const int bh = blockIdx.y;
  const unsigned short* Qp = Qg  + (size_t)bh * SEQ * HDIM;
  const unsigned short* Kp = Kg  + (size_t)bh * SEQ * HDIM;
  const unsigned short* Vp = VTg + (size_t)bh * HDIM * SEQ;   // [d][s]
  const int b = bh >> 4, h = bh & 15;
  const float C2 = 0.18033688f;   // 0.125 * log2(e)

  // per-lane invariant staging geometry (chunks j=0,1)
  int sRow[2], sSwz[2], sDst[2];
#pragma unroll
  for (int j = 0; j < 2; ++j) {
    int c = j * 256 + tid;
    sRow[j] = c >> 3;
    sSwz[j] = (((c & 7) * 16) ^ ((sRow[j] & 7) << 4)) >> 1;   // elems
    sDst[j] = (j * 256 + wid * 64) * 8;                       // elems
  }
  // precomputed LDS read byte-offsets (same for K and V^T: rows lq / lq+32)
  int off0[4], off1[4];
#pragma unroll
  for (int ks = 0; ks < 4; ++ks) {
    int col = ks * 32 + hi * 16;
    off0[ks] = lq * 128 + (col ^ ((lq & 7) << 4));
    off1[ks] = (lq + 32) * 128 + (col ^ ((lq & 7) << 4));  // (lq+32)&7 == lq&7
  }

  for (int half = 0; half < 2; ++half) {
    const int qb = half == 0 ? (int)blockIdx.x : (NQB - 1 - (int)blockIdx.x);
    const int qw0 = qb * 128 + wid * 32;       // warp's first q row

    // staging source pointers, advanced per stage call
    const unsigned short* kSrc[2];
    const unsigned short* vSrc[2];
#pragma unroll
    for (int j = 0; j < 2; ++j) {
      kSrc[j] = Kp + (size_t)sRow[j] * HDIM + sSwz[j];
      vSrc[j] = Vp + (size_t)sRow[j] * SEQ + sSwz[j];
    }
    auto stageKV = [&](int buf) {
#pragma unroll
      for (int j = 0; j < 2; ++j) {
        gload16(kSrc[j], smem + buf * 4096 + sDst[j]);
        kSrc[j] += 64 * HDIM;
      }
#pragma unroll
      for (int j = 0; j < 2; ++j) {
        gload16(vSrc[j], smem + 12288 + buf * 4096 + sDst[j]);
        vSrc[j] += 64;
      }
    };

    // Q B-frags: lane q=lq, d = ks*16 + hi*8 + j
    bf16x8 qf[4];
    {
      const unsigned short* qrow = Qp + (size_t)(qw0 + lq) * HDIM + hi * 8;
#pragma unroll
      for (int ks = 0; ks < 4; ++ks) qf[ks] = *(const bf16x8*)(qrow + ks * 16);
    }

    f32x16 o0 = zero16(), o1 = zero16();
    float m_run = -INFINITY, l_run = 0.f, mc2 = 0.f;
    const int nt = 2 * qb + 2;

    // prologue: stage tiles 0,1 (nt >= 2 always)
    stageKV(0); stageKV(1);
    asm volatile("s_waitcnt vmcnt(4)" ::: "memory");
    __builtin_amdgcn_s_barrier();

    for (int t = 0; t < nt; ++t) {
      const int cur = t % 3;
      const bool pf = (t + 2) < nt;
      if (pf) stageKV((t + 2) % 3);

      if (t * 64 <= qw0 + 31) {   // warp has at least one visible key in this tile
        // ---- QK^T: S^T[64 key][32 q], lane owns q=lq; keys split lane<->lane+32 ----
        const char* Kl = (const char*)smem + cur * 8192;
        f32x16 s0 = zero16(), s1 = zero16();
        __builtin_amdgcn_s_setprio(1);
#pragma unroll
        for (int ks = 0; ks < 4; ++ks) {
          bf16x8 a0 = *(const bf16x8*)(Kl + off0[ks]);
          bf16x8 a1 = *(const bf16x8*)(Kl + off1[ks]);
          s0 = mfma32(a0, qf[ks], s0);
          s1 = mfma32(a1, qf[ks], s1);
        }
        __builtin_amdgcn_s_setprio(0);

        // ---- causal mask (raw scores; 1/8 scale folded into exp) ----
        if (t * 64 + 63 > qw0) {
          const int q = qw0 + lq;
          const int kb = t * 64 + 4 * hi;
#pragma unroll
          for (int r = 0; r < 16; ++r) {
            int k0 = kb + (r & 3) + 8 * (r >> 2);
            if (k0 > q)      s0[r] = -INFINITY;
            if (k0 + 32 > q) s1[r] = -INFINITY;
          }
        }

        // ---- online softmax, lane-local + 1 cross-half exchange ----
        float pmax = fmaxf(s0[0], s0[1]);
#pragma unroll
        for (int r = 2; r < 16; r += 2) pmax = fmaxf(pmax, fmaxf(s0[r], s0[r + 1]));
#pragma unroll
        for (int r = 0; r < 16; r += 2) pmax = fmaxf(pmax, fmaxf(s1[r], s1[r + 1]));
        pmax = fmaxf(pmax, __shfl_xor(pmax, 32, 64));

        if (!__all(pmax - m_run <= 64.0f)) {     // defer-max THR: e^(64*0.125)=e^8
          float mn = fmaxf(m_run, pmax);
          float alpha = exp2v((m_run - mn) * C2);
          l_run *= alpha;
#pragma unroll
          for (int r = 0; r < 16; ++r) { o0[r] *= alpha; o1[r] *= alpha; }
          m_run = mn;
          mc2 = mn * C2;
        }

        float rsum = 0.f;
#pragma unroll
        for (int r = 0; r < 16; ++r) {
          float p = exp2v(__builtin_fmaf(s0[r], C2, -mc2));
          s0[r] = p; rsum += p;
        }
#pragma unroll
        for (int r = 0; r < 16; ++r) {
          float p = exp2v(__builtin_fmaf(s1[r], C2, -mc2));
          s1[r] = p; rsum += p;
        }
        rsum += __shfl_xor(rsum, 32, 64);
        l_run += rsum;

        // ---- P -> bf16 B-frags via cvt_pk + permlane32_swap (T12) ----
        bf16x8 pfr[4];
#pragma unroll
        for (int h2 = 0; h2 < 2; ++h2) {
          {
            unsigned va = cvtpk(s0[h2 * 8 + 0], s0[h2 * 8 + 1]);
            unsigned vb = cvtpk(s0[h2 * 8 + 4], s0[h2 * 8 + 5]);
            unsigned vc = cvtpk(s0[h2 * 8 + 2], s0[h2 * 8 + 3]);
            unsigned vd = cvtpk(s0[h2 * 8 + 6], s0[h2 * 8 + 7]);
            permswap(va, vb); permswap(vc, vd);
            u32x4 tt; tt.x = va; tt.y = vc; tt.z = vb; tt.w = vd;
            pfr[h2] = __builtin_bit_cast(bf16x8, tt);
          }
          {
            unsigned va = cvtpk(s1[h2 * 8 + 0], s1[h2 * 8 + 1]);
            unsigned vb = cvtpk(s1[h2 * 8 + 4], s1[h2 * 8 + 5]);
            unsigned vc = cvtpk(s1[h2 * 8 + 2], s1[h2 * 8 + 3]);
            unsigned vd = cvtpk(s1[h2 * 8 + 6], s1[h2 * 8 + 7]);
            permswap(va, vb); permswap(vc, vd);
            u32x4 tt; tt.x = va; tt.y = vc; tt.z = vb; tt.w = vd;
            pfr[2 + h2] = __builtin_bit_cast(bf16x8, tt);
          }
        }

        // ---- PV: O^T[64 d][32 q] += V^T * P^T ----
        const char* Vl = (const char*)smem + 24576 + cur * 8192;
        __builtin_amdgcn_s_setprio(1);
#pragma unroll
        for (int ks = 0; ks < 4; ++ks) {
          bf16x8 va0 = *(const bf16x8*)(Vl + off0[ks]);
          bf16x8 va1 = *(const bf16x8*)(Vl + off1[ks]);
          o0 = mfma32(va0, pfr[ks], o0);
          o1 = mfma32(va1, pfr[ks], o1);
        }
        __builtin_amdgcn_s_setprio(0);
      }

      // wait-then-barrier: own tile-(t+1) stores drained; tile-(t+2) stays in flight
      if (pf) asm volatile("s_waitcnt vmcnt(4)" ::: "memory");
      else    asm volatile("s_waitcnt vmcnt(0)" ::: "memory");
      __builtin_amdgcn_s_barrier();
    }

    // ---- epilogue: normalize, bounce through LDS, coalesced store [B,S,D] ----
    const float invl = 1.0f / l_run;
    unsigned short* Ot = smem;            // [128 q][64 d] bf16, XOR-swizzled rows
    const int q = wid * 32 + lq;
#pragma unroll
    for (int r2 = 0; r2 < 16; r2 += 2) {
      int d = (r2 & 3) + 8 * (r2 >> 2) + 4 * hi;
      unsigned w0 = cvtpk(o0[r2] * invl, o0[r2 + 1] * invl);
      *(unsigned*)((char*)Ot + q * 128 + ((2 * d) ^ ((q & 7) << 4))) = w0;
      int d2 = d + 32;
      unsigned w1 = cvtpk(o1[r2] * invl, o1[r2 + 1] * invl);
      *(unsigned*)((char*)Ot + q * 128 + ((2 * d2) ^ ((q & 7) << 4))) = w1;
    }
    __syncthreads();

#pragma unroll
    for (int i = 0; i < 4; ++i) {
      int idx = i * 256 + tid;
      int qq = idx >> 3, c16 = (idx & 7) * 8;
      bf16x8 v = *(const bf16x8*)((const char*)Ot + qq * 128 + ((2 * c16) ^ ((qq & 7) << 4)));
      *(bf16x8*)(ctx + ((size_t)(b * SEQ) + qb * 128 + qq) * DM + h * 64 + c16) = v;
    }
    __syncthreads();   // protect smem before next half's staging
  }
}

// ---------------- launch ----------------
extern "C" void kernel_launch(void* const* d_in, const int* in_sizes, int n_in,
                              void* d_out, int out_size, void* d_ws, size_t ws_size,
                              hipStream_t stream)
{
  (void)in_sizes; (void)n_in; (void)out_size; (void)ws_size;
  const float* x  = (const float*)d_in[0];
  const float* Wq = (const float*)d_in[1];
  const float* Wk = (const float*)d_in[2];
  const float* Wv = (const float*)d_in[3];
  const float* Wo = (const float*)d_in[4];
  const float* bo = (const float*)d_in[5];
  float* out = (float*)d_out;

  char* ws = (char*)d_ws;
  unsigned short* xb  = (unsigned short*)(ws);                        // 16 MiB (x bf16; reused as V^T)
  unsigned short* Wqb = (unsigned short*)(ws + (size_t)16 * 1048576);
  unsigned short* Wkb = (unsigned short*)(ws + (size_t)18 * 1048576);
  unsigned short* Wvb = (unsigned short*)(ws + (size_t)20 * 1048576);
  unsigned short* Wob = (unsigned short*)(ws + (size_t)22 * 1048576);
  unsigned short* Qd  = (unsigned short*)(ws + (size_t)24 * 1048576); // [B,H,S,HD]
  unsigned short* Kd  = (unsigned short*)(ws + (size_t)40 * 1048576);
  unsigned short* Vd  = (unsigned short*)(ws + (size_t)56 * 1048576);
  unsigned short* ctxb= (unsigned short*)(ws + (size_t)72 * 1048576); // [B,S,D]
  unsigned short* VT  = xb;                                           // [B,H,HD,S] (x dead after gemm_qkv)

  cvt_f32_bf16<<<2048, 256, 0, stream>>>(x, xb, MROWS * DM / 4);
  cvt_w4<<<dim3(64, 4), 256, 0, stream>>>(Wq, Wk, Wv, Wo, Wqb, Wkb, Wvb, Wob, DM * DM / 4);

  gemm_qkv<<<dim3(MROWS / 128, DM / 128, 3), 256, 0, stream>>>(xb, Wqb, Wkb, Wvb, Qd, Kd, Vd);
  transpose_v<<<dim3(SEQ / 64, BATCH * NH), 256, 0, stream>>>(Vd, VT);
  attn_fwd3<<<dim3(NQB / 2, BATCH * NH), 256, 0, stream>>>(Qd, Kd, VT, ctxb);
  gemm_out<<<dim3(MROWS / 128, DM / 128, 1), 256, 0, stream>>>(ctxb, Wob, bo, out);
}